// Round 1
// baseline (298.448 us; speedup 1.0000x reference)
//
#include <hip/hip_runtime.h>
#include <cstdint>
#include <cstddef>

// FeatureAttention: x[4,2048,1024] fp32; Q=xWq^T+bq, K=xWk^T+bk, V=xWv^T+bv;
// out = softmax(QK^T/32) V.  All matmuls in bf16 MFMA (fp32 accum); error
// budget analysis: ~2e-4 absmax vs 1.9e-3 threshold.
//
// Workspace layout (needs 80 MB):
//   [0,16M)   Xb   (x in bf16)          -- dead after Vt GEMM
//   [16,18M)  Wqb  [18,20M) Wkb  [20,22M) Wvb
//   [32,48M)  Qb   [48,64M) Kb   (bf16)
//   [64,80M)  Vt   (V transposed, [1024][8192] bf16: Vt[u][b*2048+s])
//   [0,32M)   Sc   (scores->attn bf16 [4][2048][2048], reuses dead Xb/W region)

typedef unsigned short ushort_t;
typedef __attribute__((ext_vector_type(8))) short short8;
typedef __attribute__((ext_vector_type(4))) float f32x4;

#define AS1 __attribute__((address_space(1)))
#define AS3 __attribute__((address_space(3)))

// fp32 -> bf16 round-to-nearest-even (bit trick; avoids hip_bf16.h API drift)
__device__ __forceinline__ ushort_t f2bf(float f) {
    unsigned int u = __float_as_uint(f);
    u += 0x7FFFu + ((u >> 16) & 1u);
    return (ushort_t)(u >> 16);
}

// async global->LDS, 16B per lane. LDS dest = uniform base + lane*16.
// AS3 pointer value == LDS byte offset (generic LDS VA low 32 bits are the
// offset on gfx9; aperture lives in the high word).
__device__ __forceinline__ void async_ld16(const void* g, unsigned lds_off) {
    __builtin_amdgcn_global_load_lds((const AS1 void*)(uintptr_t)g,
                                     (AS3 void*)(uintptr_t)lds_off,
                                     16, 0, 0);
}

// ---------------------------------------------------------------------------
// BT-GEMM: C[m*ldc+n] = scale * sum_k A[m*lda+k] * B[n*ldb+k]  (+ bias)
// BIAS: 0 none, 1 bias[n], 2 bias[m].  OT: ushort_t (bf16 bits) or float.
// 128x128 tile, BK=32, 4 waves each computing a 64x64 quadrant (4x4 MFMA
// tiles of 16x16x32 bf16).  m97-style: global_load_lds staging, 2 barriers.
// Grid: (N/128, M/128, Z) with per-Z element offsets.
// ---------------------------------------------------------------------------
template <typename OT, int BIAS>
__global__ __launch_bounds__(256) void gemm_bt(
    const ushort_t* __restrict__ A, const ushort_t* __restrict__ B,
    const float* __restrict__ bias, OT* __restrict__ C,
    int K, int lda, int ldb, int ldc, float scale,
    long long aOffZ, long long bOffZ, long long cOffZ)
{
    __shared__ __align__(16) ushort_t As[128 * 32];  // 8 KB
    __shared__ __align__(16) ushort_t Bs[128 * 32];  // 8 KB

    const int tid  = threadIdx.x;
    const int wave = tid >> 6;
    const int lane = tid & 63;

    A += (size_t)blockIdx.z * aOffZ;
    B += (size_t)blockIdx.z * bOffZ;
    C += (size_t)blockIdx.z * cOffZ;

    const int m0 = blockIdx.y * 128;
    const int n0 = blockIdx.x * 128;
    const int wm = (wave >> 1) * 64;   // wave's quadrant
    const int wn = (wave & 1) * 64;

    const unsigned ldsA = (unsigned)(uintptr_t)&As[0];
    const unsigned ldsB = (unsigned)(uintptr_t)&Bs[0];

    // staging map: issue covers 64 rows; wave w lane l -> row w*16+l/4, col (l%4)*8
    const int srow = (wave << 4) + (lane >> 2);
    const int scol = (lane & 3) << 3;
    const ushort_t* gA0 = A + (size_t)(m0 + srow) * lda + scol;
    const ushort_t* gA1 = gA0 + (size_t)64 * lda;
    const ushort_t* gB0 = B + (size_t)(n0 + srow) * ldb + scol;
    const ushort_t* gB1 = gB0 + (size_t)64 * ldb;
    const unsigned lA0 = ldsA + (wave << 10);
    const unsigned lA1 = lA0 + 4096;
    const unsigned lB0 = ldsB + (wave << 10);
    const unsigned lB1 = lB0 + 4096;

    // MFMA fragment map (16x16x32): lane l -> row l&15, k = (l>>4)*8 .. +8
    const int frow = lane & 15;
    const int fko  = (lane >> 4) << 3;

    f32x4 acc[4][4] = {};

    for (int k0 = 0; k0 < K; k0 += 32) {
        if (k0) __syncthreads();                 // prev iter's ds_reads done
        async_ld16(gA0, lA0);
        async_ld16(gA1, lA1);
        async_ld16(gB0, lB0);
        async_ld16(gB1, lB1);
        gA0 += 32; gA1 += 32; gB0 += 32; gB1 += 32;
        __syncthreads();                         // vmcnt(0) drain -> LDS ready

        short8 af[4], bfr[4];
#pragma unroll
        for (int i = 0; i < 4; ++i)
            af[i] = *(const short8*)&As[(wm + i * 16 + frow) * 32 + fko];
#pragma unroll
        for (int j = 0; j < 4; ++j)
            bfr[j] = *(const short8*)&Bs[(wn + j * 16 + frow) * 32 + fko];

#pragma unroll
        for (int i = 0; i < 4; ++i)
#pragma unroll
            for (int j = 0; j < 4; ++j)
                acc[i][j] = __builtin_amdgcn_mfma_f32_16x16x32_bf16(
                    af[i], bfr[j], acc[i][j], 0, 0, 0);
    }

    // C/D layout: lane l reg r -> row (l>>4)*4+r, col l&15  (verified m89/m91)
    const int r0 = (lane >> 4) << 2;
    const int c0 = lane & 15;
#pragma unroll
    for (int i = 0; i < 4; ++i) {
#pragma unroll
        for (int j = 0; j < 4; ++j) {
            const int n = n0 + wn + j * 16 + c0;
            const float bn = (BIAS == 1) ? bias[n] : 0.f;
#pragma unroll
            for (int r = 0; r < 4; ++r) {
                const int m = m0 + wm + i * 16 + r0 + r;
                float v = acc[i][j][r] * scale + bn;
                if (BIAS == 2) v += bias[m];
                if constexpr (sizeof(OT) == 2)
                    C[(size_t)m * ldc + n] = f2bf(v);
                else
                    C[(size_t)m * ldc + n] = v;
            }
        }
    }
}

// fp32 -> bf16 bulk cast, 8 elems/thread (n % 8 == 0)
__global__ __launch_bounds__(256) void cvt_f32_bf16(
    const float* __restrict__ in, ushort_t* __restrict__ out, int n)
{
    const int i = (blockIdx.x * 256 + threadIdx.x) * 8;
    if (i >= n) return;
    const f32x4 a = *(const f32x4*)(in + i);
    const f32x4 b = *(const f32x4*)(in + i + 4);
    short8 o;
    o[0] = (short)f2bf(a[0]); o[1] = (short)f2bf(a[1]);
    o[2] = (short)f2bf(a[2]); o[3] = (short)f2bf(a[3]);
    o[4] = (short)f2bf(b[0]); o[5] = (short)f2bf(b[1]);
    o[6] = (short)f2bf(b[2]); o[7] = (short)f2bf(b[3]);
    *(short8*)(out + i) = o;
}

// in-place row softmax over bf16 [8192][2048]; one block per row
__global__ __launch_bounds__(256) void softmax_rows(ushort_t* __restrict__ S)
{
    const int tid = threadIdx.x;
    ushort_t* p = S + (size_t)blockIdx.x * 2048 + tid * 8;
    const short8 raw = *(const short8*)p;
    float v[8];
#pragma unroll
    for (int j = 0; j < 8; ++j)
        v[j] = __uint_as_float(((unsigned)(ushort_t)raw[j]) << 16);

    float mx = v[0];
#pragma unroll
    for (int j = 1; j < 8; ++j) mx = fmaxf(mx, v[j]);
#pragma unroll
    for (int off = 32; off > 0; off >>= 1) mx = fmaxf(mx, __shfl_xor(mx, off, 64));

    __shared__ float red[8];
    const int wave = tid >> 6, lane = tid & 63;
    if (lane == 0) red[wave] = mx;
    __syncthreads();
    mx = fmaxf(fmaxf(red[0], red[1]), fmaxf(red[2], red[3]));

    float s = 0.f;
#pragma unroll
    for (int j = 0; j < 8; ++j) { v[j] = __expf(v[j] - mx); s += v[j]; }
#pragma unroll
    for (int off = 32; off > 0; off >>= 1) s += __shfl_xor(s, off, 64);
    if (lane == 0) red[4 + wave] = s;
    __syncthreads();
    s = (red[4] + red[5]) + (red[6] + red[7]);

    const float inv = 1.0f / s;
    short8 o;
#pragma unroll
    for (int j = 0; j < 8; ++j) o[j] = (short)f2bf(v[j] * inv);
    *(short8*)p = o;
}

extern "C" void kernel_launch(void* const* d_in, const int* in_sizes, int n_in,
                              void* d_out, int out_size, void* d_ws, size_t ws_size,
                              hipStream_t stream)
{
    const float* x  = (const float*)d_in[0];
    const float* Wq = (const float*)d_in[1];
    const float* bq = (const float*)d_in[2];
    const float* Wk = (const float*)d_in[3];
    const float* bk = (const float*)d_in[4];
    const float* Wv = (const float*)d_in[5];
    const float* bv = (const float*)d_in[6];
    float* out = (float*)d_out;

    char* ws = (char*)d_ws;
    const size_t MB = 1ull << 20;
    ushort_t* Xb  = (ushort_t*)(ws);            // 16 MB
    ushort_t* Wqb = (ushort_t*)(ws + 16 * MB);  // 2 MB
    ushort_t* Wkb = (ushort_t*)(ws + 18 * MB);  // 2 MB
    ushort_t* Wvb = (ushort_t*)(ws + 20 * MB);  // 2 MB
    ushort_t* Qb  = (ushort_t*)(ws + 32 * MB);  // 16 MB
    ushort_t* Kb  = (ushort_t*)(ws + 48 * MB);  // 16 MB
    ushort_t* Vt  = (ushort_t*)(ws + 64 * MB);  // 16 MB
    ushort_t* Sc  = (ushort_t*)(ws);            // 32 MB, reuses Xb/W after proj

    // 1) casts to bf16
    cvt_f32_bf16<<<dim3(4096), dim3(256), 0, stream>>>(x, Xb, 8388608);
    cvt_f32_bf16<<<dim3(512), dim3(256), 0, stream>>>(Wq, Wqb, 1048576);
    cvt_f32_bf16<<<dim3(512), dim3(256), 0, stream>>>(Wk, Wkb, 1048576);
    cvt_f32_bf16<<<dim3(512), dim3(256), 0, stream>>>(Wv, Wvb, 1048576);

    // 2) Q = X Wq^T + bq  [8192,1024] bf16 ; K likewise
    gemm_bt<ushort_t, 1><<<dim3(8, 64, 1), dim3(256), 0, stream>>>(
        Xb, Wqb, bq, Qb, 1024, 1024, 1024, 1024, 1.0f, 0, 0, 0);
    gemm_bt<ushort_t, 1><<<dim3(8, 64, 1), dim3(256), 0, stream>>>(
        Xb, Wkb, bk, Kb, 1024, 1024, 1024, 1024, 1.0f, 0, 0, 0);

    // 3) Vt = Wv X^T + bv(row)  [1024,8192] bf16  (V transposed for PV GEMM)
    gemm_bt<ushort_t, 2><<<dim3(64, 8, 1), dim3(256), 0, stream>>>(
        Wvb, Xb, bv, Vt, 1024, 1024, 1024, 8192, 1.0f, 0, 0, 0);

    // 4) scores = Q K^T / 32  per batch -> bf16 [4][2048][2048]
    gemm_bt<ushort_t, 0><<<dim3(16, 16, 4), dim3(256), 0, stream>>>(
        Qb, Kb, nullptr, Sc, 1024, 1024, 1024, 2048, 0.03125f,
        2048ll * 1024, 2048ll * 1024, 2048ll * 2048);

    // 5) softmax rows in place
    softmax_rows<<<dim3(8192), dim3(256), 0, stream>>>(Sc);

    // 6) out = attn V = attn (Vt)^T -> fp32 d_out
    gemm_bt<float, 0><<<dim3(8, 16, 4), dim3(256), 0, stream>>>(
        Sc, Vt, nullptr, out, 2048, 2048, 8192, 1024, 1.0f,
        2048ll * 2048, 2048ll, 2048ll * 1024);
}

// Round 3
// 256.967 us; speedup vs baseline: 1.1614x; 1.1614x over previous
//
#include <hip/hip_runtime.h>
#include <cstdint>
#include <cstddef>

// FeatureAttention: x[4,2048,1024] fp32; Q=xWq^T+bq, K=xWk^T+bk, V=xWv^T+bv;
// out = softmax(QK^T/32) V.  bf16 MFMA pipeline.
//
// R3: fix R2's batch bug — PV epilogue must read rowsum[z*2048+m], not
// rowsum[m].  (R2 absmax 5.9e-3 == batches 1-3 divided by batch 0's sums.)
//
// Workspace (80 MB):
//   [0,16M)  Xb    [16,18) Wqb  [18,20) Wkb  [20,22) Wvb   (dead after proj)
//   [32,48M) Qb    [48,64M) Kb   (dead after scores)
//   [64,80M) Vt    (V transposed [1024][8192])
//   [0,32M)  Sc    (exp(scores) bf16 [4][2048][2048], reuses dead region)
//   [32M,+32KB) rowsum fp32[8192]  (reuses dead Qb, written after scores)

typedef unsigned short ushort_t;
typedef __attribute__((ext_vector_type(8))) short short8;
typedef __attribute__((ext_vector_type(4))) float f32x4;

#define AS1 __attribute__((address_space(1)))
#define AS3 __attribute__((address_space(3)))

__device__ __forceinline__ ushort_t f2bf(float f) {
    unsigned int u = __float_as_uint(f);
    u += 0x7FFFu + ((u >> 16) & 1u);
    return (ushort_t)(u >> 16);
}
__device__ __forceinline__ float bf2f(ushort_t b) {
    return __uint_as_float(((unsigned)b) << 16);
}

// async global->LDS, 16B/lane; lds dest = wave-uniform base + lane*16
__device__ __forceinline__ void async_ld16(const void* g, unsigned lds_off) {
    __builtin_amdgcn_global_load_lds((const AS1 void*)(uintptr_t)g,
                                     (AS3 void*)(uintptr_t)lds_off,
                                     16, 0, 0);
}

// ---------------------------------------------------------------------------
// BT-GEMM, 128x128 tile, NB outputs sharing the A tile.
//   C_o[m*ldc+n] = epi( scale * sum_k A[m*lda+k] * B_o[n*ldb+k] )
// EPI: 0 none | 1 +bias_o[n] | 2 +bias0[m] | 3 exp(v) | 4 v/bias0[z*biasOffZ+m]
// Bank swizzle: 16B chunk c of row r stored at position (c+r)&(P-1), P=BK/8.
// Applied on the staging *source* col so global_load_lds's fixed lane->LDS
// map is preserved; fragment reads apply the same permutation.
// ---------------------------------------------------------------------------
template <typename OT, int EPI, int NB, int BK>
__global__ __launch_bounds__(256, 2) void gemm_bt(
    const ushort_t* __restrict__ A, const ushort_t* __restrict__ B0,
    const ushort_t* __restrict__ B1,
    const float* __restrict__ bias0, const float* __restrict__ bias1,
    OT* __restrict__ C0, OT* __restrict__ C1,
    int K, int lda, int ldb, int ldc, float scale,
    long long aOffZ, long long bOffZ, long long cOffZ, long long biasOffZ)
{
    constexpr int P     = BK / 8;    // 16B positions per row
    constexpr int NCALL = BK / 16;   // staging calls per 128-row tile
    constexpr int RPC   = 2048 / BK; // rows per staging call (4 waves)

    __shared__ __align__(16) ushort_t As[128 * BK];
    __shared__ __align__(16) ushort_t Bs[NB][128 * BK];

    const int tid  = threadIdx.x;
    const int wave = tid >> 6;
    const int lane = tid & 63;

    A  += (size_t)blockIdx.z * aOffZ;
    B0 += (size_t)blockIdx.z * bOffZ;
    if (NB == 2) B1 += (size_t)blockIdx.z * bOffZ;
    bias0 += (size_t)blockIdx.z * biasOffZ;

    const int m0 = blockIdx.y * 128;
    const int n0 = blockIdx.x * 128;
    const int wm = (wave >> 1) * 64;
    const int wn = (wave & 1) * 64;

    const unsigned ldsA  = (unsigned)(uintptr_t)&As[0];
    const unsigned ldsB0 = (unsigned)(uintptr_t)&Bs[0][0];
    const unsigned ldsB1 = (NB == 2) ? (unsigned)(uintptr_t)&Bs[NB - 1][0] : 0;

    // staging map: row-in-call, swizzled source chunk
    const int srow = wave * (RPC / 4) + lane / P;
    const int cd   = ((lane & (P - 1)) - srow) & (P - 1);
    const ushort_t* gA  = A  + (size_t)(m0 + srow) * lda + cd * 8;
    const ushort_t* gB0 = B0 + (size_t)(n0 + srow) * ldb + cd * 8;
    const ushort_t* gB1 = (NB == 2) ? B1 + (size_t)(n0 + srow) * ldb + cd * 8
                                    : nullptr;
    const unsigned lw = (wave << 10);

    // fragment map: lane -> row l&15; chunk (t*4 + l>>4) at swizzled pos
    const int frow = lane & 15;
    const int fg   = lane >> 4;

    f32x4 acc[NB][4][4] = {};

    for (int k0 = 0; k0 < K; k0 += BK) {
        if (k0) __syncthreads();
#pragma unroll
        for (int c = 0; c < NCALL; ++c) {
            const size_t ro = (size_t)c * RPC;
            async_ld16(gA + ro * lda, ldsA + c * 4096 + lw);
            async_ld16(gB0 + ro * ldb, ldsB0 + c * 4096 + lw);
            if (NB == 2) async_ld16(gB1 + ro * ldb, ldsB1 + c * 4096 + lw);
        }
        gA += BK; gB0 += BK; if (NB == 2) gB1 += BK;
        __syncthreads();

#pragma unroll
        for (int t = 0; t < BK / 32; ++t) {
            const int pa = (((t << 2) + fg + frow) & (P - 1)) << 3;
            short8 af[4], bf[4];
#pragma unroll
            for (int i = 0; i < 4; ++i)
                af[i] = *(const short8*)&As[(wm + i * 16 + frow) * BK + pa];
#pragma unroll
            for (int j = 0; j < 4; ++j)
                bf[j] = *(const short8*)&Bs[0][(wn + j * 16 + frow) * BK + pa];
#pragma unroll
            for (int i = 0; i < 4; ++i)
#pragma unroll
                for (int j = 0; j < 4; ++j)
                    acc[0][i][j] = __builtin_amdgcn_mfma_f32_16x16x32_bf16(
                        af[i], bf[j], acc[0][i][j], 0, 0, 0);
            if (NB == 2) {
#pragma unroll
                for (int j = 0; j < 4; ++j)
                    bf[j] = *(const short8*)&Bs[NB - 1][(wn + j * 16 + frow) * BK + pa];
#pragma unroll
                for (int i = 0; i < 4; ++i)
#pragma unroll
                    for (int j = 0; j < 4; ++j)
                        acc[NB - 1][i][j] = __builtin_amdgcn_mfma_f32_16x16x32_bf16(
                            af[i], bf[j], acc[NB - 1][i][j], 0, 0, 0);
            }
        }
    }

    // C/D layout: lane l reg r -> row (l>>4)*4+r, col l&15
    const int r0 = (lane >> 4) << 2;
    const int c0 = lane & 15;
#pragma unroll
    for (int o = 0; o < NB; ++o) {
        OT* C = (o == 0) ? C0 : C1;
        C += (size_t)blockIdx.z * cOffZ;
        const float* bia = (o == 0) ? bias0 : bias1;
#pragma unroll
        for (int i = 0; i < 4; ++i) {
            float bm[4];
            if (EPI == 2 || EPI == 4) {
#pragma unroll
                for (int r = 0; r < 4; ++r)
                    bm[r] = bias0[m0 + wm + i * 16 + r0 + r];
                if (EPI == 4) {
#pragma unroll
                    for (int r = 0; r < 4; ++r) bm[r] = 1.0f / bm[r];
                }
            }
#pragma unroll
            for (int j = 0; j < 4; ++j) {
                const int n = n0 + wn + j * 16 + c0;
                const float bn = (EPI == 1) ? bia[n] : 0.f;
#pragma unroll
                for (int r = 0; r < 4; ++r) {
                    const int m = m0 + wm + i * 16 + r0 + r;
                    float v = acc[o][i][j][r] * scale;
                    if (EPI == 1) v += bn;
                    if (EPI == 2) v += bm[r];
                    if (EPI == 3) v = __expf(v);
                    if (EPI == 4) v *= bm[r];
                    if constexpr (sizeof(OT) == 2)
                        C[(size_t)m * ldc + n] = f2bf(v);
                    else
                        C[(size_t)m * ldc + n] = v;
                }
            }
        }
    }
}

// fp32 -> bf16 bulk cast, 8 elems/thread
__global__ __launch_bounds__(256) void cvt_f32_bf16(
    const float* __restrict__ in, ushort_t* __restrict__ out, int n)
{
    const int i = (blockIdx.x * 256 + threadIdx.x) * 8;
    if (i >= n) return;
    const f32x4 a = *(const f32x4*)(in + i);
    const f32x4 b = *(const f32x4*)(in + i + 4);
    short8 o;
    o[0] = (short)f2bf(a[0]); o[1] = (short)f2bf(a[1]);
    o[2] = (short)f2bf(a[2]); o[3] = (short)f2bf(a[3]);
    o[4] = (short)f2bf(b[0]); o[5] = (short)f2bf(b[1]);
    o[6] = (short)f2bf(b[2]); o[7] = (short)f2bf(b[3]);
    *(short8*)(out + i) = o;
}

// rowsum over bf16 [8192][2048] -> fp32[8192]; one block per row
__global__ __launch_bounds__(256) void rowsum_rows(
    const ushort_t* __restrict__ S, float* __restrict__ rs)
{
    const int tid = threadIdx.x;
    const ushort_t* p = S + (size_t)blockIdx.x * 2048 + tid * 8;
    const short8 raw = *(const short8*)p;
    float s = 0.f;
#pragma unroll
    for (int j = 0; j < 8; ++j) s += bf2f((ushort_t)raw[j]);
#pragma unroll
    for (int off = 32; off > 0; off >>= 1) s += __shfl_xor(s, off, 64);
    __shared__ float red[4];
    const int wave = tid >> 6, lane = tid & 63;
    if (lane == 0) red[wave] = s;
    __syncthreads();
    if (tid == 0) rs[blockIdx.x] = (red[0] + red[1]) + (red[2] + red[3]);
}

extern "C" void kernel_launch(void* const* d_in, const int* in_sizes, int n_in,
                              void* d_out, int out_size, void* d_ws, size_t ws_size,
                              hipStream_t stream)
{
    const float* x  = (const float*)d_in[0];
    const float* Wq = (const float*)d_in[1];
    const float* bq = (const float*)d_in[2];
    const float* Wk = (const float*)d_in[3];
    const float* bk = (const float*)d_in[4];
    const float* Wv = (const float*)d_in[5];
    const float* bv = (const float*)d_in[6];
    float* out = (float*)d_out;

    char* ws = (char*)d_ws;
    const size_t MB = 1ull << 20;
    ushort_t* Xb  = (ushort_t*)(ws);
    ushort_t* Wqb = (ushort_t*)(ws + 16 * MB);
    ushort_t* Wkb = (ushort_t*)(ws + 18 * MB);
    ushort_t* Wvb = (ushort_t*)(ws + 20 * MB);
    ushort_t* Qb  = (ushort_t*)(ws + 32 * MB);
    ushort_t* Kb  = (ushort_t*)(ws + 48 * MB);
    ushort_t* Vt  = (ushort_t*)(ws + 64 * MB);
    ushort_t* Sc  = (ushort_t*)(ws);             // reuses dead Xb/W region
    float*    Rs  = (float*)(ws + 32 * MB);      // reuses dead Qb region

    // 1) casts
    cvt_f32_bf16<<<dim3(4096), dim3(256), 0, stream>>>(x, Xb, 8388608);
    cvt_f32_bf16<<<dim3(512), dim3(256), 0, stream>>>(Wq, Wqb, 1048576);
    cvt_f32_bf16<<<dim3(512), dim3(256), 0, stream>>>(Wk, Wkb, 1048576);
    cvt_f32_bf16<<<dim3(512), dim3(256), 0, stream>>>(Wv, Wvb, 1048576);

    // 2) fused Q,K projection: stage X once, two weight tiles
    gemm_bt<ushort_t, 1, 2, 64><<<dim3(8, 64, 1), dim3(256), 0, stream>>>(
        Xb, Wqb, Wkb, bq, bk, Qb, Kb, 1024, 1024, 1024, 1024, 1.0f,
        0, 0, 0, 0);

    // 3) Vt = Wv X^T + bv(row)  [1024,8192]
    gemm_bt<ushort_t, 2, 1, 64><<<dim3(64, 8, 1), dim3(256), 0, stream>>>(
        Wvb, Xb, nullptr, bv, nullptr, Vt, nullptr,
        1024, 1024, 1024, 8192, 1.0f, 0, 0, 0, 0);

    // 4) Sc = exp(Q K^T / 32)  per batch (max-free softmax numerator)
    gemm_bt<ushort_t, 3, 1, 32><<<dim3(16, 16, 4), dim3(256), 0, stream>>>(
        Qb, Kb, nullptr, nullptr, nullptr, Sc, nullptr,
        1024, 1024, 1024, 2048, 0.03125f,
        2048ll * 1024, 2048ll * 1024, 2048ll * 2048, 0);

    // 5) rowsum of Sc
    rowsum_rows<<<dim3(8192), dim3(256), 0, stream>>>(Sc, Rs);

    // 6) out = (Sc Vt^T) / rowsum[z*2048+m]
    gemm_bt<float, 4, 1, 64><<<dim3(8, 16, 4), dim3(256), 0, stream>>>(
        Sc, Vt, nullptr, Rs, nullptr, out, nullptr,
        2048, 2048, 8192, 1024, 1.0f,
        2048ll * 2048, 2048ll, 2048ll * 1024, 2048);
}

// Round 4
// 249.851 us; speedup vs baseline: 1.1945x; 1.0285x over previous
//
#include <hip/hip_runtime.h>
#include <cstdint>
#include <cstddef>

// FeatureAttention: x[4,2048,1024] fp32; Q=xWq^T+bq, K=xWk^T+bk, V=xWv^T+bv;
// out = softmax(QK^T/32) V.  bf16 MFMA pipeline.
//
// R4: scores GEMM BK=32->64 (32 MFMA per barrier); rowsum fused into PV
// (A-tile streams every Sc row element once -> register rowsum -> LDS ->
// epilogue divide); 4 cast kernels merged into 1. 9 launches -> 5.
//
// Workspace (80 MB):
//   [0,16M)  Xb    [16,18) Wqb  [18,20) Wkb  [20,22) Wvb   (dead after proj)
//   [32,48M) Qb    [48,64M) Kb   (dead after scores)
//   [64,80M) Vt    (V transposed [1024][8192])
//   [0,32M)  Sc    (exp(scores) bf16 [4][2048][2048], reuses dead region)

typedef unsigned short ushort_t;
typedef __attribute__((ext_vector_type(8))) short short8;
typedef __attribute__((ext_vector_type(4))) float f32x4;

#define AS1 __attribute__((address_space(1)))
#define AS3 __attribute__((address_space(3)))

__device__ __forceinline__ ushort_t f2bf(float f) {
    unsigned int u = __float_as_uint(f);
    u += 0x7FFFu + ((u >> 16) & 1u);
    return (ushort_t)(u >> 16);
}
__device__ __forceinline__ float bf2f(ushort_t b) {
    return __uint_as_float(((unsigned)b) << 16);
}

// async global->LDS, 16B/lane; lds dest = wave-uniform base + lane*16
__device__ __forceinline__ void async_ld16(const void* g, unsigned lds_off) {
    __builtin_amdgcn_global_load_lds((const AS1 void*)(uintptr_t)g,
                                     (AS3 void*)(uintptr_t)lds_off,
                                     16, 0, 0);
}

// ---------------------------------------------------------------------------
// BT-GEMM, 128x128 tile, NB outputs sharing the A tile.
//   C_o[m*ldc+n] = epi( scale * sum_k A[m*lda+k] * B_o[n*ldb+k] )
// EPI: 0 none | 1 +bias_o[n] | 2 +bias0[m] | 3 exp(v)
//      | 4 v / rowsum(A-tile row m)   (rowsum computed in-kernel)
// Bank swizzle: 16B chunk c of row r stored at position (c+r)&(P-1), P=BK/8,
// applied on the staging *source* col (global_load_lds lane->LDS map fixed).
// ---------------------------------------------------------------------------
template <typename OT, int EPI, int NB, int BK>
__global__ __launch_bounds__(256, 2) void gemm_bt(
    const ushort_t* __restrict__ A, const ushort_t* __restrict__ B0,
    const ushort_t* __restrict__ B1,
    const float* __restrict__ bias0, const float* __restrict__ bias1,
    OT* __restrict__ C0, OT* __restrict__ C1,
    int K, int lda, int ldb, int ldc, float scale,
    long long aOffZ, long long bOffZ, long long cOffZ)
{
    constexpr int P     = BK / 8;    // 16B positions per row
    constexpr int NCALL = BK / 16;   // staging calls per 128-row tile
    constexpr int RPC   = 2048 / BK; // rows per staging call (4 waves)

    __shared__ __align__(16) ushort_t As[128 * BK];
    __shared__ __align__(16) ushort_t Bs[NB][128 * BK];
    __shared__ float rs[128];        // EPI==4 only (512 B)

    const int tid  = threadIdx.x;
    const int wave = tid >> 6;
    const int lane = tid & 63;

    A  += (size_t)blockIdx.z * aOffZ;
    B0 += (size_t)blockIdx.z * bOffZ;
    if (NB == 2) B1 += (size_t)blockIdx.z * bOffZ;

    const int m0 = blockIdx.y * 128;
    const int n0 = blockIdx.x * 128;
    const int wm = (wave >> 1) * 64;
    const int wn = (wave & 1) * 64;

    const unsigned ldsA  = (unsigned)(uintptr_t)&As[0];
    const unsigned ldsB0 = (unsigned)(uintptr_t)&Bs[0][0];
    const unsigned ldsB1 = (NB == 2) ? (unsigned)(uintptr_t)&Bs[NB - 1][0] : 0;

    // staging map: row-in-call, swizzled source chunk
    const int srow = wave * (RPC / 4) + lane / P;
    const int cd   = ((lane & (P - 1)) - srow) & (P - 1);
    const ushort_t* gA  = A  + (size_t)(m0 + srow) * lda + cd * 8;
    const ushort_t* gB0 = B0 + (size_t)(n0 + srow) * ldb + cd * 8;
    const ushort_t* gB1 = (NB == 2) ? B1 + (size_t)(n0 + srow) * ldb + cd * 8
                                    : nullptr;
    const unsigned lw = (wave << 10);

    // fragment map: lane -> row l&15; chunk (t*4 + l>>4) at swizzled pos
    const int frow = lane & 15;
    const int fg   = lane >> 4;

    f32x4 acc[NB][4][4] = {};
    float rsacc[4] = {0.f, 0.f, 0.f, 0.f};

    for (int k0 = 0; k0 < K; k0 += BK) {
        if (k0) __syncthreads();
#pragma unroll
        for (int c = 0; c < NCALL; ++c) {
            const size_t ro = (size_t)c * RPC;
            async_ld16(gA + ro * lda, ldsA + c * 4096 + lw);
            async_ld16(gB0 + ro * ldb, ldsB0 + c * 4096 + lw);
            if (NB == 2) async_ld16(gB1 + ro * ldb, ldsB1 + c * 4096 + lw);
        }
        gA += BK; gB0 += BK; if (NB == 2) gB1 += BK;
        __syncthreads();

#pragma unroll
        for (int t = 0; t < BK / 32; ++t) {
            const int pa = (((t << 2) + fg + frow) & (P - 1)) << 3;
            short8 af[4], bf[4];
#pragma unroll
            for (int i = 0; i < 4; ++i)
                af[i] = *(const short8*)&As[(wm + i * 16 + frow) * BK + pa];
            if (EPI == 4 && wn == 0) {   // rowsum of the streamed A tile
#pragma unroll
                for (int i = 0; i < 4; ++i)
#pragma unroll
                    for (int e = 0; e < 8; ++e)
                        rsacc[i] += bf2f((ushort_t)af[i][e]);
            }
#pragma unroll
            for (int j = 0; j < 4; ++j)
                bf[j] = *(const short8*)&Bs[0][(wn + j * 16 + frow) * BK + pa];
#pragma unroll
            for (int i = 0; i < 4; ++i)
#pragma unroll
                for (int j = 0; j < 4; ++j)
                    acc[0][i][j] = __builtin_amdgcn_mfma_f32_16x16x32_bf16(
                        af[i], bf[j], acc[0][i][j], 0, 0, 0);
            if (NB == 2) {
#pragma unroll
                for (int j = 0; j < 4; ++j)
                    bf[j] = *(const short8*)&Bs[NB - 1][(wn + j * 16 + frow) * BK + pa];
#pragma unroll
                for (int i = 0; i < 4; ++i)
#pragma unroll
                    for (int j = 0; j < 4; ++j)
                        acc[NB - 1][i][j] = __builtin_amdgcn_mfma_f32_16x16x32_bf16(
                            af[i], bf[j], acc[NB - 1][i][j], 0, 0, 0);
            }
        }
    }

    if (EPI == 4) {
        if (wn == 0) {
#pragma unroll
            for (int i = 0; i < 4; ++i) {
                float s = rsacc[i];
                s += __shfl_xor(s, 16, 64);
                s += __shfl_xor(s, 32, 64);
                rs[wm + i * 16 + frow] = s;   // 4 lanes, same value/addr
            }
        }
        __syncthreads();
    }

    // C/D layout: lane l reg r -> row (l>>4)*4+r, col l&15
    const int r0 = (lane >> 4) << 2;
    const int c0 = lane & 15;
#pragma unroll
    for (int o = 0; o < NB; ++o) {
        OT* C = (o == 0) ? C0 : C1;
        C += (size_t)blockIdx.z * cOffZ;
        const float* bia = (o == 0) ? bias0 : bias1;
#pragma unroll
        for (int i = 0; i < 4; ++i) {
            float bm[4];
            if (EPI == 2) {
#pragma unroll
                for (int r = 0; r < 4; ++r)
                    bm[r] = bias0[m0 + wm + i * 16 + r0 + r];
            }
            if (EPI == 4) {
#pragma unroll
                for (int r = 0; r < 4; ++r)
                    bm[r] = 1.0f / rs[wm + i * 16 + r0 + r];
            }
#pragma unroll
            for (int j = 0; j < 4; ++j) {
                const int n = n0 + wn + j * 16 + c0;
                const float bn = (EPI == 1) ? bia[n] : 0.f;
#pragma unroll
                for (int r = 0; r < 4; ++r) {
                    const int m = m0 + wm + i * 16 + r0 + r;
                    float v = acc[o][i][j][r] * scale;
                    if (EPI == 1) v += bn;
                    if (EPI == 2) v += bm[r];
                    if (EPI == 3) v = __expf(v);
                    if (EPI == 4) v *= bm[r];
                    if constexpr (sizeof(OT) == 2)
                        C[(size_t)m * ldc + n] = f2bf(v);
                    else
                        C[(size_t)m * ldc + n] = v;
                }
            }
        }
    }
}

// one-shot fp32->bf16 cast of x, Wq, Wk, Wv (block-range dispatch)
__global__ __launch_bounds__(256) void cvt_all(
    const float* __restrict__ x,  const float* __restrict__ wq,
    const float* __restrict__ wk, const float* __restrict__ wv,
    ushort_t* __restrict__ xb,  ushort_t* __restrict__ wqb,
    ushort_t* __restrict__ wkb, ushort_t* __restrict__ wvb)
{
    const int b = blockIdx.x;
    const float* src; ushort_t* dst; size_t base;
    if (b < 4096)      { src = x;  dst = xb;  base = (size_t)b * 2048; }
    else if (b < 4608) { src = wq; dst = wqb; base = (size_t)(b - 4096) * 2048; }
    else if (b < 5120) { src = wk; dst = wkb; base = (size_t)(b - 4608) * 2048; }
    else               { src = wv; dst = wvb; base = (size_t)(b - 5120) * 2048; }
    const size_t i = base + threadIdx.x * 8;
    const f32x4 a = *(const f32x4*)(src + i);
    const f32x4 c = *(const f32x4*)(src + i + 4);
    short8 o;
    o[0] = (short)f2bf(a[0]); o[1] = (short)f2bf(a[1]);
    o[2] = (short)f2bf(a[2]); o[3] = (short)f2bf(a[3]);
    o[4] = (short)f2bf(c[0]); o[5] = (short)f2bf(c[1]);
    o[6] = (short)f2bf(c[2]); o[7] = (short)f2bf(c[3]);
    *(short8*)(dst + i) = o;
}

extern "C" void kernel_launch(void* const* d_in, const int* in_sizes, int n_in,
                              void* d_out, int out_size, void* d_ws, size_t ws_size,
                              hipStream_t stream)
{
    const float* x  = (const float*)d_in[0];
    const float* Wq = (const float*)d_in[1];
    const float* bq = (const float*)d_in[2];
    const float* Wk = (const float*)d_in[3];
    const float* bk = (const float*)d_in[4];
    const float* Wv = (const float*)d_in[5];
    const float* bv = (const float*)d_in[6];
    float* out = (float*)d_out;

    char* ws = (char*)d_ws;
    const size_t MB = 1ull << 20;
    ushort_t* Xb  = (ushort_t*)(ws);
    ushort_t* Wqb = (ushort_t*)(ws + 16 * MB);
    ushort_t* Wkb = (ushort_t*)(ws + 18 * MB);
    ushort_t* Wvb = (ushort_t*)(ws + 20 * MB);
    ushort_t* Qb  = (ushort_t*)(ws + 32 * MB);
    ushort_t* Kb  = (ushort_t*)(ws + 48 * MB);
    ushort_t* Vt  = (ushort_t*)(ws + 64 * MB);
    ushort_t* Sc  = (ushort_t*)(ws);             // reuses dead Xb/W region

    // 1) all casts in one launch
    cvt_all<<<dim3(5632), dim3(256), 0, stream>>>(
        x, Wq, Wk, Wv, Xb, Wqb, Wkb, Wvb);

    // 2) fused Q,K projection: stage X once, two weight tiles
    gemm_bt<ushort_t, 1, 2, 64><<<dim3(8, 64, 1), dim3(256), 0, stream>>>(
        Xb, Wqb, Wkb, bq, bk, Qb, Kb, 1024, 1024, 1024, 1024, 1.0f, 0, 0, 0);

    // 3) Vt = Wv X^T + bv(row)  [1024,8192]
    gemm_bt<ushort_t, 2, 1, 64><<<dim3(64, 8, 1), dim3(256), 0, stream>>>(
        Wvb, Xb, nullptr, bv, nullptr, Vt, nullptr,
        1024, 1024, 1024, 8192, 1.0f, 0, 0, 0);

    // 4) Sc = exp(Q K^T / 32)  per batch (max-free softmax numerator)
    gemm_bt<ushort_t, 3, 1, 64><<<dim3(16, 16, 4), dim3(256), 0, stream>>>(
        Qb, Kb, nullptr, nullptr, nullptr, Sc, nullptr,
        1024, 1024, 1024, 2048, 0.03125f,
        2048ll * 1024, 2048ll * 1024, 2048ll * 2048);

    // 5) out = (Sc Vt^T) / rowsum(Sc row), rowsum fused in-kernel
    gemm_bt<float, 4, 1, 64><<<dim3(8, 16, 4), dim3(256), 0, stream>>>(
        Sc, Vt, nullptr, nullptr, nullptr, out, nullptr,
        2048, 2048, 8192, 1024, 1.0f,
        2048ll * 2048, 2048ll, 2048ll * 1024);
}